// Round 1
// baseline (6015.537 us; speedup 1.0000x reference)
//
#include <hip/hip_runtime.h>
#include <hip/hip_fp16.h>
#include <cstdint>
#include <cstddef>

typedef _Float16 f16;
typedef __attribute__((ext_vector_type(8))) _Float16 f16x8;
typedef __attribute__((ext_vector_type(4))) _Float16 f16x4;
typedef __attribute__((ext_vector_type(4))) float f32x4;

#define B_SZ 256
#define T_IN 1024
#define W_CH 512
#define U_N  512
#define P_K  16
#define TP   1009            // T_IN - P_K + 1
#define MROWS (B_SZ * TP)    // 258304

// ---------------------------------------------------------------------------
// Weight convert + transpose: fp32 [k][n] -> f16 [n][k]  (for contiguous-k
// MFMA B-fragments: frag = Wt[n = lane&15][k = 8*(lane>>4)+j], 16B per lane)
// ---------------------------------------------------------------------------
__global__ __launch_bounds__(256) void k_convert(
    const float* __restrict__ kern, const float* __restrict__ rec,
    f16* __restrict__ Kt, f16* __restrict__ Rt) {
  int idx = blockIdx.x * 256 + threadIdx.x;   // 0 .. 2*2^18
  int which = idx >> 18;
  int e = idx & 262143;
  int n = e >> 9;
  int k = e & 511;
  if (which == 0) Kt[(size_t)n * 512 + k] = (f16)kern[(size_t)k * 512 + n];
  else            Rt[(size_t)n * 512 + k] = (f16)rec [(size_t)k * 512 + n];
}

// ---------------------------------------------------------------------------
// PSC conv: syn[b,t,w] = psc_b + sum_k psc_w[k] * x[b,t+k,w]   (f16 out)
// Thread owns (b, w-quad) and marches 64 t's with a 16-deep float4 ring.
// ---------------------------------------------------------------------------
__global__ __launch_bounds__(256) void k_conv(
    const float* __restrict__ x, const float* __restrict__ psc_w,
    const float* __restrict__ psc_b, f16* __restrict__ syn) {
  int g  = blockIdx.x * 256 + threadIdx.x;
  int wq = g & 127;              // w quad (4 floats)
  int tt = (g >> 7) & 15;        // t tile of 64
  int b  = g >> 11;
  int t0 = tt * 64;
  const float4* xr = (const float4*)x + (size_t)b * T_IN * 128 + wq;
  float wgt[16];
#pragma unroll
  for (int k = 0; k < 16; ++k) wgt[k] = psc_w[k];
  float b0 = psc_b[0];
  float4 win[16];
#pragma unroll
  for (int i = 0; i < 15; ++i) win[i] = xr[(size_t)(t0 + i) * 128];
  f16* sp = syn + ((size_t)b * TP + t0) * 512 + wq * 4;
  int steps = TP - t0; if (steps > 64) steps = 64;   // wave-uniform
  for (int j0 = 0; j0 < 64; j0 += 16) {
#pragma unroll
    for (int jj = 0; jj < 16; ++jj) {
      int j = j0 + jj;
      if (j < steps) {
        win[(j + 15) & 15] = xr[(size_t)(t0 + j + 15) * 128];
        float ax = b0, ay = b0, az = b0, aw = b0;
#pragma unroll
        for (int k = 0; k < 16; ++k) {
          float4 v = win[(j + k) & 15];
          float wk = wgt[k];
          ax += wk * v.x; ay += wk * v.y; az += wk * v.z; aw += wk * v.w;
        }
        f16x4 o; o.x = (f16)ax; o.y = (f16)ay; o.z = (f16)az; o.w = (f16)aw;
        *(f16x4*)(sp + (size_t)j * 512) = o;
      }
    }
  }
}

// ---------------------------------------------------------------------------
// Xp = syn @ K + bias  (fp32 result written into d_out, overwritten later by
// the recurrent kernel in place).  128x128 tile, BK=32, mfma 16x16x32 f16.
// ---------------------------------------------------------------------------
__global__ __launch_bounds__(256) void k_gemm(
    const f16* __restrict__ syn, const f16* __restrict__ Kt,
    const float* __restrict__ bias, float* __restrict__ out) {
  int bid = blockIdx.x;
  size_t m0 = (size_t)(bid >> 2) * 128;
  int n0 = (bid & 3) * 128;
  int tid = threadIdx.x;
  int wave = tid >> 6, lane = tid & 63;
  int q = lane >> 4, l15 = lane & 15;
  __shared__ f16 lA[128 * 32];
  __shared__ f16 lB[128 * 32];
  f32x4 acc[8][2] = {};
  int s0 = tid, s1 = tid + 256;
  int rA0 = s0 >> 2, cA0 = (s0 & 3) * 8;
  int rA1 = s1 >> 2, cA1 = (s1 & 3) * 8;
  for (int k0 = 0; k0 < 512; k0 += 32) {
    f16x8 a0 = *(const f16x8*)(syn + (m0 + rA0) * 512 + k0 + cA0);
    f16x8 a1 = *(const f16x8*)(syn + (m0 + rA1) * 512 + k0 + cA1);
    f16x8 b0 = *(const f16x8*)(Kt + (size_t)(n0 + rA0) * 512 + k0 + cA0);
    f16x8 b1 = *(const f16x8*)(Kt + (size_t)(n0 + rA1) * 512 + k0 + cA1);
    __syncthreads();                       // previous tile fully consumed
    *(f16x8*)(lA + s0 * 8) = a0;  *(f16x8*)(lA + s1 * 8) = a1;
    *(f16x8*)(lB + s0 * 8) = b0;  *(f16x8*)(lB + s1 * 8) = b1;
    __syncthreads();
    f16x8 bf[2];
#pragma unroll
    for (int j = 0; j < 2; ++j)
      bf[j] = *(const f16x8*)(lB + (wave * 32 + j * 16 + l15) * 32 + q * 8);
#pragma unroll
    for (int i = 0; i < 8; ++i) {
      f16x8 af = *(const f16x8*)(lA + (i * 16 + l15) * 32 + q * 8);
      acc[i][0] = __builtin_amdgcn_mfma_f32_16x16x32_f16(af, bf[0], acc[i][0], 0, 0, 0);
      acc[i][1] = __builtin_amdgcn_mfma_f32_16x16x32_f16(af, bf[1], acc[i][1], 0, 0, 0);
    }
  }
#pragma unroll
  for (int j = 0; j < 2; ++j) {
    int col = n0 + wave * 32 + j * 16 + l15;
    float bv = bias[col];
#pragma unroll
    for (int i = 0; i < 8; ++i) {
      size_t row = m0 + i * 16 + q * 4;
#pragma unroll
      for (int r = 0; r < 4; ++r)
        out[(row + r) * 512 + col] = acc[i][j][r] + bv;
    }
  }
}

// ---------------------------------------------------------------------------
// Sequential recurrence.  32 blocks x 8 batches, 512 threads (8 waves); wave
// owns 64 output units.  R split: kk0..8 in VGPRs (144/lane), kk9 in LDS,
// kk10..15 streamed from L2 with a 2-deep window.  State round-trips via LDS.
// Reads Xp from io (=d_out) and overwrites it with n in place.
// ---------------------------------------------------------------------------
__global__ __launch_bounds__(512, 2) void k_rnn(
    const f16* __restrict__ Rt, float* __restrict__ io) {
  int b0 = blockIdx.x * 8;
  int tid = threadIdx.x, wave = tid >> 6, lane = tid & 63;
  int q = lane >> 4, l15 = lane & 15;
  __shared__ f16 S[16 * 520];     // state [m][k], stride 520 halfs (1040 B)
  __shared__ f16 RL[512 * 40];    // R cols k in [288,320), stride 40 halfs

  for (int i = tid; i < 16 * 520; i += 512) S[i] = (f16)0.f;
  {
    int n = tid;                  // 512 threads <-> 512 rows
    const f16x8* src = (const f16x8*)(Rt + (size_t)n * 512 + 288);
    f16x8* dst = (f16x8*)(RL + n * 40);
#pragma unroll
    for (int c = 0; c < 4; ++c) dst[c] = src[c];
  }
  const f16* rbase = Rt + (size_t)(wave * 64 + l15) * 512 + q * 8;
  f16x8 rs[9][4];
#pragma unroll
  for (int kk = 0; kk < 9; ++kk)
#pragma unroll
    for (int nt = 0; nt < 4; ++nt)
      rs[kk][nt] = *(const f16x8*)(rbase + (size_t)nt * 8192 + kk * 32);

  bool active = (q < 2);
  float* iobase[4];
#pragma unroll
  for (int i = 0; i < 4; ++i) {
    int mm = (q * 4 + i) & 7;     // inactive lanes mirror active ones (L2 hit)
    iobase[i] = io + (size_t)(b0 + mm) * TP * 512 + wave * 64 + l15;
  }
  float xp[4][4];
#pragma unroll
  for (int i = 0; i < 4; ++i)
#pragma unroll
    for (int nt = 0; nt < 4; ++nt) xp[i][nt] = iobase[i][nt * 16];

  const f16* abase = S + l15 * 520 + q * 8;
  __syncthreads();

  for (int t = 0; t < TP; ++t) {
    f32x4 acc[4] = {};
    f16x8 sA[4], sB[4];                                   // L2 stream window
#pragma unroll
    for (int nt = 0; nt < 4; ++nt) sA[nt] = *(const f16x8*)(rbase + (size_t)nt * 8192 + 10 * 32);
#pragma unroll
    for (int nt = 0; nt < 4; ++nt) sB[nt] = *(const f16x8*)(rbase + (size_t)nt * 8192 + 11 * 32);
#pragma unroll
    for (int kk = 0; kk < 9; ++kk) {                      // register-resident R
      f16x8 af = *(const f16x8*)(abase + kk * 32);
#pragma unroll
      for (int nt = 0; nt < 4; ++nt)
        acc[nt] = __builtin_amdgcn_mfma_f32_16x16x32_f16(af, rs[kk][nt], acc[nt], 0, 0, 0);
    }
    {                                                     // kk=9 from LDS
      f16x8 af = *(const f16x8*)(abase + 9 * 32);
#pragma unroll
      for (int nt = 0; nt < 4; ++nt) {
        f16x8 bf = *(const f16x8*)(RL + (wave * 64 + nt * 16 + l15) * 40 + q * 8);
        acc[nt] = __builtin_amdgcn_mfma_f32_16x16x32_f16(af, bf, acc[nt], 0, 0, 0);
      }
    }
    {                                                     // kk=10, refill kk=12
      f16x8 af = *(const f16x8*)(abase + 10 * 32);
#pragma unroll
      for (int nt = 0; nt < 4; ++nt) acc[nt] = __builtin_amdgcn_mfma_f32_16x16x32_f16(af, sA[nt], acc[nt], 0, 0, 0);
#pragma unroll
      for (int nt = 0; nt < 4; ++nt) sA[nt] = *(const f16x8*)(rbase + (size_t)nt * 8192 + 12 * 32);
    }
    {                                                     // kk=11, refill kk=13
      f16x8 af = *(const f16x8*)(abase + 11 * 32);
#pragma unroll
      for (int nt = 0; nt < 4; ++nt) acc[nt] = __builtin_amdgcn_mfma_f32_16x16x32_f16(af, sB[nt], acc[nt], 0, 0, 0);
#pragma unroll
      for (int nt = 0; nt < 4; ++nt) sB[nt] = *(const f16x8*)(rbase + (size_t)nt * 8192 + 13 * 32);
    }
    {                                                     // kk=12, refill kk=14
      f16x8 af = *(const f16x8*)(abase + 12 * 32);
#pragma unroll
      for (int nt = 0; nt < 4; ++nt) acc[nt] = __builtin_amdgcn_mfma_f32_16x16x32_f16(af, sA[nt], acc[nt], 0, 0, 0);
#pragma unroll
      for (int nt = 0; nt < 4; ++nt) sA[nt] = *(const f16x8*)(rbase + (size_t)nt * 8192 + 14 * 32);
    }
    {                                                     // kk=13, refill kk=15
      f16x8 af = *(const f16x8*)(abase + 13 * 32);
#pragma unroll
      for (int nt = 0; nt < 4; ++nt) acc[nt] = __builtin_amdgcn_mfma_f32_16x16x32_f16(af, sB[nt], acc[nt], 0, 0, 0);
#pragma unroll
      for (int nt = 0; nt < 4; ++nt) sB[nt] = *(const f16x8*)(rbase + (size_t)nt * 8192 + 15 * 32);
    }
    {                                                     // kk=14
      f16x8 af = *(const f16x8*)(abase + 14 * 32);
#pragma unroll
      for (int nt = 0; nt < 4; ++nt) acc[nt] = __builtin_amdgcn_mfma_f32_16x16x32_f16(af, sA[nt], acc[nt], 0, 0, 0);
    }
    {                                                     // kk=15
      f16x8 af = *(const f16x8*)(abase + 15 * 32);
#pragma unroll
      for (int nt = 0; nt < 4; ++nt) acc[nt] = __builtin_amdgcn_mfma_f32_16x16x32_f16(af, sB[nt], acc[nt], 0, 0, 0);
    }
    // epilogue: out -> n (store), soft-reset state (reuse xp regs for state)
#pragma unroll
    for (int i = 0; i < 4; ++i) {
#pragma unroll
      for (int nt = 0; nt < 4; ++nt) {
        float o  = acc[nt][i] + xp[i][nt];
        float en = __builtin_amdgcn_exp2f(-4.3280850f * o);     // exp(-3o)
        float n  = __builtin_amdgcn_rcpf(1.f + en);             // sigmoid(3o)
        float eg = __builtin_amdgcn_exp2f((2.f * n - 1.f) * 1.4426950f); // exp(2n-1)
        float g  = __builtin_amdgcn_rcpf(1.f + eg);             // sigmoid(1-2n)
        if (active) iobase[i][nt * 16] = n;                     // n overwrites Xp
        xp[i][nt] = o * g;                                      // new state
      }
    }
    __syncthreads();                      // everyone done reading S this step
    if (active) {
#pragma unroll
      for (int i = 0; i < 4; ++i)
#pragma unroll
        for (int nt = 0; nt < 4; ++nt)
          S[(q * 4 + i) * 520 + wave * 64 + nt * 16 + l15] = (f16)xp[i][nt];
    }
    __syncthreads();                      // S fully updated
#pragma unroll
    for (int i = 0; i < 4; ++i) iobase[i] += 512;
    if (t < TP - 1) {                     // prefetch Xp[t+1]
#pragma unroll
      for (int i = 0; i < 4; ++i)
#pragma unroll
        for (int nt = 0; nt < 4; ++nt) xp[i][nt] = iobase[i][nt * 16];
    }
  }
}

// ---------------------------------------------------------------------------
extern "C" void kernel_launch(void* const* d_in, const int* in_sizes, int n_in,
                              void* d_out, int out_size, void* d_ws, size_t ws_size,
                              hipStream_t stream) {
  (void)in_sizes; (void)n_in; (void)out_size; (void)ws_size;
  const float* x     = (const float*)d_in[0];
  const float* psc_w = (const float*)d_in[1];
  const float* psc_b = (const float*)d_in[2];
  const float* kern  = (const float*)d_in[3];
  const float* rec   = (const float*)d_in[4];
  const float* bias  = (const float*)d_in[5];
  float* out = (float*)d_out;
  char* ws = (char*)d_ws;
  // ws layout: syn f16 (258304*512*2 = 264,503,296 B) | Kt f16 512KB | Rt f16 512KB
  f16* syn = (f16*)ws;
  f16* Kt  = (f16*)(ws + 264503296ull);
  f16* Rt  = (f16*)(ws + 265027584ull);

  k_convert<<<2048, 256, 0, stream>>>(kern, rec, Kt, Rt);
  k_conv   <<<2048, 256, 0, stream>>>(x, psc_w, psc_b, syn);
  k_gemm   <<<2018 * 4, 256, 0, stream>>>(syn, Kt, bias, out);
  k_rnn    <<<32, 512, 0, stream>>>(Rt, out);
}